// Round 4
// baseline (2132.815 us; speedup 1.0000x reference)
//
#include <hip/hip_runtime.h>
#include <math.h>

#define L_ 6
#define H_ 8
#define D_HD 64
#define E_ 512
#define V_ 32000
#define S_ 2048
#define B_ 2
#define M_ (B_*S_)   // 4096 rows

typedef float  floatx4 __attribute__((ext_vector_type(4)));
typedef short  shortx8 __attribute__((ext_vector_type(8)));
typedef short  shortx4 __attribute__((ext_vector_type(4)));

__device__ __forceinline__ short f2bf(float f){
  unsigned u = __builtin_bit_cast(unsigned, f);
  u += 0x7FFFu + ((u >> 16) & 1u);   // round-to-nearest-even
  return (short)(u >> 16);
}
__device__ __forceinline__ float bf2f(short s){
  unsigned u = ((unsigned)(unsigned short)s) << 16;
  return __builtin_bit_cast(float, u);
}
__device__ __forceinline__ float gelu_exact(float x){
  return 0.5f * x * (1.0f + erff(x * 0.70710678118654752440f));
}

typedef const __attribute__((address_space(1))) unsigned int* gas_p;
typedef __attribute__((address_space(3))) unsigned int* las_p;
__device__ __forceinline__ void gl16(const void* g, void* l){
  __builtin_amdgcn_global_load_lds((gas_p)g, (las_p)l, 16, 0, 0);
}

// XOR bank swizzle for 128B-row LDS tiles (attention K/V/P tiles)
__device__ __forceinline__ char* lds_at(void* base, int row, int colByte){
  return (char*)base + (((row << 7) + colByte) ^ ((row & 7) << 4));
}

// ---------------- embedding: x = tok_emb[id]/sqrt(E) + pos_emb[s] ----------
__global__ __launch_bounds__(128) void embed_k(const int* __restrict__ ids,
                                               const float* __restrict__ tok,
                                               const float* __restrict__ pos,
                                               float* __restrict__ x){
  int row = blockIdx.x;
  int s   = row & (S_ - 1);
  int id  = ids[row];
  const float4* te = (const float4*)(tok + (long long)id * E_);
  const float4* pe = (const float4*)(pos + (long long)s  * E_);
  float4 a = te[threadIdx.x];
  float4 b = pe[threadIdx.x];
  const float isq = 0.04419417382415922f;  // 1/sqrt(512)
  float4 o = { a.x*isq + b.x, a.y*isq + b.y, a.z*isq + b.z, a.w*isq + b.w };
  ((float4*)(x + (long long)row * E_))[threadIdx.x] = o;
}

// ---------------- LayerNorm, bf16 output (rounding point == old staging) ---
__global__ __launch_bounds__(128) void ln_k(const float* __restrict__ x,
                                            const float* __restrict__ g,
                                            short* __restrict__ out){
  int row = blockIdx.x, tid = threadIdx.x;
  int lane = tid & 63, wid = tid >> 6;
  float4 v = ((const float4*)(x + (long long)row * E_))[tid];
  float s  = v.x + v.y + v.z + v.w;
  float sq = v.x*v.x + v.y*v.y + v.z*v.z + v.w*v.w;
  #pragma unroll
  for(int off = 32; off > 0; off >>= 1){
    s  += __shfl_xor(s,  off, 64);
    sq += __shfl_xor(sq, off, 64);
  }
  __shared__ float ss[2], sqs[2];
  if(lane == 0){ ss[wid] = s; sqs[wid] = sq; }
  __syncthreads();
  s = ss[0] + ss[1]; sq = sqs[0] + sqs[1];
  float mu  = s * (1.0f / E_);
  float var = sq * (1.0f / E_) - mu * mu;
  float rs  = rsqrtf(var + 1e-6f);
  float4 gv = ((const float4*)g)[tid];
  shortx4 ob = { f2bf((v.x-mu)*rs*gv.x), f2bf((v.y-mu)*rs*gv.y),
                 f2bf((v.z-mu)*rs*gv.z), f2bf((v.w-mu)*rs*gv.w) };
  ((shortx4*)(out + (long long)row * E_))[tid] = ob;
}

// ---------------- weight transpose+convert: Wt[n][k] = bf16(W[k][n]) -------
__global__ __launch_bounds__(256) void transpose_k(const float* __restrict__ W,
                                                   short* __restrict__ Wt,
                                                   int K, int N){
  __shared__ short t[64][68];
  int tid = threadIdx.x;
  int r16 = tid >> 4, c4 = (tid & 15) * 4;
  long long base = (long long)blockIdx.z * K * N;
  int n0 = blockIdx.x * 64, k0 = blockIdx.y * 64;
  #pragma unroll
  for(int ph = 0; ph < 4; ph++){
    int row = ph*16 + r16;
    float4 v = *(const float4*)(W + base + (long long)(k0+row)*N + n0 + c4);
    t[row][c4+0]=f2bf(v.x); t[row][c4+1]=f2bf(v.y);
    t[row][c4+2]=f2bf(v.z); t[row][c4+3]=f2bf(v.w);
  }
  __syncthreads();
  #pragma unroll
  for(int ph = 0; ph < 4; ph++){
    int orow = ph*16 + r16;   // n-local
    shortx4 o = { t[c4+0][orow], t[c4+1][orow], t[c4+2][orow], t[c4+3][orow] };
    *(shortx4*)(Wt + base + (long long)(n0+orow)*K + k0 + c4) = o;
  }
}

// ---------------- MFMA GEMM, bf16 A x bf16 Wt^T, 128xBN tile, BK=64 --------
// BK=64 realized as TWO independent [rows][32] sub-tiles (64B rows), each
// with the proven <=2-way swizzle; halves the barrier count per unit K.
template<int BN>
__global__ __launch_bounds__(256) void gemm_bf_k(const short* __restrict__ A,
                                                 const short* __restrict__ Wt,
                                                 const float* __restrict__ bias,
                                                 const float* __restrict__ res,
                                                 void* __restrict__ Cout,
                                                 int M, int N, int K,
                                                 int act, int outbf){
  constexpr int NT = BN / 32;         // n-fragments per wave
  constexpr int BHALF = BN * 64;      // bytes per B sub-tile
  __shared__ short As[8192];          // 2 x [128][32] bf16, swizzled (16 KB)
  __shared__ short Bs[BN*64];         // 2 x [BN][32]  bf16, swizzled
  int tid = threadIdx.x;
  int wave = tid >> 6, lane = tid & 63, quad = lane >> 4, l16 = lane & 15;
  int wr = wave >> 1, wc = wave & 1;

  int MT  = M >> 7;
  int nwg = gridDim.x, bid = blockIdx.x;
  int nb  = bid;
  if((nwg & 7) == 0) nb = (bid & 7) * (nwg >> 3) + (bid >> 3);
  long long m0 = (long long)(nb % MT) << 7;
  long long n0 = (long long)(nb / MT) * BN;

  // staging: lds byte tid*16 (+4096 for issue 1) <-> row=tid>>2, slot=tid&3;
  // source chunk gq = slot ^ f(row), f(row)=(row&3)^((row>>2)&3)
  int rs = tid >> 2;
  int gq = (tid & 3) ^ ((tid >> 2) & 3) ^ ((tid >> 4) & 3);
  const short* a0 = A  + (m0 + rs)      * (long long)K + gq * 8;
  const short* a1 = A  + (m0 + rs + 64) * (long long)K + gq * 8;
  const short* b0 = Wt + (n0 + rs)      * (long long)K + gq * 8;
  const short* b1 = (BN == 128) ? Wt + (n0 + rs + 64) * (long long)K + gq * 8 : nullptr;
  char* dA = (char*)As + wave * 1024;
  char* dB = (char*)Bs + wave * 1024;

  int aoff[4], boff[NT];
  #pragma unroll
  for(int t = 0; t < 4; t++){
    int ra = wr*64 + t*16 + l16;
    aoff[t] = ra*64 + ((quad ^ (ra & 3) ^ ((ra >> 2) & 3)) << 4);
  }
  #pragma unroll
  for(int t = 0; t < NT; t++){
    int rb = wc*(BN/2) + t*16 + l16;
    boff[t] = rb*64 + ((quad ^ (rb & 3) ^ ((rb >> 2) & 3)) << 4);
  }

  floatx4 acc[4][NT];
  #pragma unroll
  for(int i = 0; i < 4; i++)
    #pragma unroll
    for(int j = 0; j < NT; j++)
      acc[i][j] = (floatx4){0.f, 0.f, 0.f, 0.f};

  for(int k0 = 0; k0 < K; k0 += 64){
    // lo sub-tile (k0..k0+31)
    gl16(a0, dA);       gl16(a1, dA + 4096);
    gl16(b0, dB);
    if(BN == 128) gl16(b1, dB + 4096);
    // hi sub-tile (k0+32..k0+63)
    gl16(a0 + 32, dA + 8192);  gl16(a1 + 32, dA + 8192 + 4096);
    gl16(b0 + 32, dB + BHALF);
    if(BN == 128) gl16(b1 + 32, dB + BHALF + 4096);
    a0 += 64; a1 += 64; b0 += 64;
    if(BN == 128) b1 += 64;
    __syncthreads();
    #pragma unroll
    for(int ks2 = 0; ks2 < 2; ks2++){
      const char* Ab = (const char*)As + ks2 * 8192;
      const char* Bb = (const char*)Bs + ks2 * BHALF;
      shortx8 af[4], bfr[NT];
      #pragma unroll
      for(int t = 0; t < 4; t++)
        af[t]  = *(const shortx8*)(Ab + aoff[t]);
      #pragma unroll
      for(int t = 0; t < NT; t++)
        bfr[t] = *(const shortx8*)(Bb + boff[t]);
      #pragma unroll
      for(int i = 0; i < 4; i++)
        #pragma unroll
        for(int j = 0; j < NT; j++)
          acc[i][j] = __builtin_amdgcn_mfma_f32_16x16x32_bf16(af[i], bfr[j], acc[i][j], 0, 0, 0);
    }
    __syncthreads();
  }

  #pragma unroll
  for(int i = 0; i < 4; i++){
    #pragma unroll
    for(int r = 0; r < 4; r++){
      long long row = m0 + wr*64 + i*16 + quad*4 + r;
      #pragma unroll
      for(int j = 0; j < NT; j++){
        long long col = n0 + wc*(BN/2) + j*16 + l16;
        float v = acc[i][j][r];
        if(bias) v += bias[col];
        if(act)  v = gelu_exact(v);
        if(res)  v += res[row * N + col];
        if(outbf) ((short*)Cout)[row * N + col] = f2bf(v);
        else      ((float*)Cout)[row * N + col] = v;
      }
    }
  }
}

// ---------------- flash attention, bf16 qkv input, MFMA 16x16x32 -----------
// Raw-unit running max (scale folded into exp FMA), defer-rescale (T13,
// raw threshold 64 -> P <= e^8), setprio around MFMA clusters (T5).
__global__ __launch_bounds__(256) void fattn_k(const short* __restrict__ qkv,
                                               short* __restrict__ out){
  __shared__ short Ks[64*64];      // K tile,  [k][d] bf16, swizzled   8KB
  __shared__ short Vt[64*64];      // V tile,  [d][k] bf16, swizzled   8KB
  __shared__ short Ps[4*16*64];    // per-wave P, [q16][k64] bf16      8KB
  int tid = threadIdx.x, wave = tid >> 6, lane = tid & 63;
  int quad = lane >> 4, l16 = lane & 15;
  int bh = blockIdx.x & 15;
  int qt = 31 - (blockIdx.x >> 4);   // heavy q-tiles dispatch first
  int b = bh >> 3, h = bh & 7;
  int q0 = qt * 64;

  const short* base = qkv + (long long)b * S_ * 1536;
  const short* Qb = base + h*64;
  const short* Kb = base + 512  + h*64;
  const short* Vb = base + 1024 + h*64;

  shortx8 qf[2];
  {
    const short* qp = Qb + (long long)(q0 + 16*wave + l16) * 1536 + quad*8;
    qf[0] = *(const shortx8*)(qp);
    qf[1] = *(const shortx8*)(qp + 32);
  }

  float m_s = -1e30f, l_s = 0.f;     // m_s in RAW score units
  floatx4 acc_o[4] = {{0,0,0,0},{0,0,0,0},{0,0,0,0},{0,0,0,0}};

  int krow   = wave*8 + (lane >> 3);
  int kchunk = (lane & 7) ^ (krow & 7);
  const short* kA = Kb + (long long)krow * 1536 + kchunk * 8;
  char* dK0 = (char*)Ks + wave * 1024;
  char* dK1 = dK0 + 4096;

  int vk4 = (tid >> 4) * 4, vd4 = (tid & 15) * 4;
  const short* vp = Vb + (long long)vk4 * 1536 + vd4;
  char* pbase = (char*)Ps + wave * 2048;

  for(int k0 = 0; k0 <= q0; k0 += 64){
    gl16(kA, dK0);
    gl16(kA + 32*1536, dK1);
    {
      shortx4 r0 = *(const shortx4*)(vp);
      shortx4 r1 = *(const shortx4*)(vp + 1536);
      shortx4 r2 = *(const shortx4*)(vp + 2*1536);
      shortx4 r3 = *(const shortx4*)(vp + 3*1536);
      shortx4 v0 = {r0[0], r1[0], r2[0], r3[0]};
      shortx4 v1 = {r0[1], r1[1], r2[1], r3[1]};
      shortx4 v2 = {r0[2], r1[2], r2[2], r3[2]};
      shortx4 v3 = {r0[3], r1[3], r2[3], r3[3]};
      *(shortx4*)lds_at(Vt, vd4+0, vk4*2) = v0;
      *(shortx4*)lds_at(Vt, vd4+1, vk4*2) = v1;
      *(shortx4*)lds_at(Vt, vd4+2, vk4*2) = v2;
      *(shortx4*)lds_at(Vt, vd4+3, vk4*2) = v3;
    }
    kA += 64*1536; vp += 64*1536;
    __syncthreads();

    floatx4 s[4] = {{0,0,0,0},{0,0,0,0},{0,0,0,0},{0,0,0,0}};
    __builtin_amdgcn_s_setprio(1);
    #pragma unroll
    for(int ks2 = 0; ks2 < 2; ks2++){
      #pragma unroll
      for(int t = 0; t < 4; t++){
        shortx8 kf = *(const shortx8*)lds_at(Ks, 16*t + l16, quad*16 + ks2*64);
        s[t] = __builtin_amdgcn_mfma_f32_16x16x32_bf16(kf, qf[ks2], s[t], 0, 0, 0);
      }
    }
    __builtin_amdgcn_s_setprio(0);

    if(k0 == q0){
      int q = q0 + 16*wave + l16;
      #pragma unroll
      for(int t = 0; t < 4; t++){
        #pragma unroll
        for(int r = 0; r < 4; r++){
          int k = k0 + 16*t + quad*4 + r;
          if(k > q) s[t][r] = -1e30f;
        }
      }
    }

    // ---- row max (raw units) ----
    float mloc = -1e30f;
    #pragma unroll
    for(int t = 0; t < 4; t++)
      mloc = fmaxf(mloc, fmaxf(fmaxf(s[t][0], s[t][1]), fmaxf(s[t][2], s[t][3])));
    mloc = fmaxf(mloc, __shfl_xor(mloc, 16, 64));
    mloc = fmaxf(mloc, __shfl_xor(mloc, 32, 64));

    // ---- defer-rescale: only rescale when max grows by >64 raw (= 8 scaled)
    if(!__all(mloc - m_s <= 64.0f)){
      float mnew  = fmaxf(m_s, mloc);
      float sc    = __expf((m_s - mnew) * 0.125f);   // 0 on first tile
      l_s *= sc;
      #pragma unroll
      for(int r = 0; r < 4; r++){
        float scr = __shfl(sc, (lane & 48) | (quad*4 + r), 64);
        #pragma unroll
        for(int t = 0; t < 4; t++) acc_o[t][r] *= scr;
      }
      m_s = mnew;
    }

    float nm = -0.125f * m_s;
    float sumloc = 0.f;
    shortx4 pw[4];
    #pragma unroll
    for(int t = 0; t < 4; t++){
      #pragma unroll
      for(int r = 0; r < 4; r++){
        float e = __expf(fmaf(s[t][r], 0.125f, nm));
        short pb = f2bf(e);
        pw[t][r] = pb;
        sumloc += bf2f(pb);
      }
    }
    sumloc += __shfl_xor(sumloc, 16, 64);
    sumloc += __shfl_xor(sumloc, 32, 64);
    l_s += sumloc;

    #pragma unroll
    for(int t = 0; t < 4; t++)
      *(shortx4*)lds_at(pbase, l16, 32*t + 8*quad) = pw[t];
    asm volatile("" ::: "memory");

    __builtin_amdgcn_s_setprio(1);
    #pragma unroll
    for(int ks2 = 0; ks2 < 2; ks2++){
      shortx8 pf = *(const shortx8*)lds_at(pbase, l16, quad*16 + ks2*64);
      #pragma unroll
      for(int t = 0; t < 4; t++){
        shortx8 vf = *(const shortx8*)lds_at(Vt, 16*t + l16, quad*16 + ks2*64);
        acc_o[t] = __builtin_amdgcn_mfma_f32_16x16x32_bf16(pf, vf, acc_o[t], 0, 0, 0);
      }
    }
    __builtin_amdgcn_s_setprio(0);
    __syncthreads();
  }

  #pragma unroll
  for(int r = 0; r < 4; r++){
    float li  = __shfl(l_s, (lane & 48) | (quad*4 + r), 64);
    float inv = 1.0f / li;
    int qrow = q0 + 16*wave + quad*4 + r;
    short* op = out + ((long long)(b*S_ + qrow)) * E_ + h*64 + l16;
    #pragma unroll
    for(int t = 0; t < 4; t++) op[16*t] = f2bf(acc_o[t][r] * inv);
  }
}

// ---------------------------------------------------------------------------
extern "C" void kernel_launch(void* const* d_in, const int* in_sizes, int n_in,
                              void* d_out, int out_size, void* d_ws, size_t ws_size,
                              hipStream_t stream){
  const int*   ids    = (const int*)d_in[0];
  const float* tok    = (const float*)d_in[1];
  const float* pos    = (const float*)d_in[2];
  const float* qkv_w  = (const float*)d_in[3];
  const float* qkv_b  = (const float*)d_in[4];
  const float* proj_w = (const float*)d_in[5];
  const float* proj_b = (const float*)d_in[6];
  const float* fc1_w  = (const float*)d_in[7];
  const float* fc1_b  = (const float*)d_in[8];
  const float* fc2_w  = (const float*)d_in[9];
  const float* fc2_b  = (const float*)d_in[10];
  const float* ln1_g  = (const float*)d_in[11];
  const float* ln2_g  = (const float*)d_in[12];
  const float* lnf_g  = (const float*)d_in[13];
  const float* out_w  = (const float*)d_in[14];
  float* logits = (float*)d_out;

  char* w = (char*)d_ws;
  float* x    = (float*)(w);                       // [4096,512]  fp32   8 MB
  short* h    = (short*)(w + (8ll  << 20));        // [4096,512]  bf16   4 MB
  short* qkvb = (short*)(w + (12ll << 20));        // [4096,1536] bf16  12 MB
  short* f1   = (short*)(w + (24ll << 20));        // [4096,2048] bf16  16 MB
  short* wpool= (short*)(w + (40ll << 20));        // bf16 Wt pool    70.6 MB
  short* qkvT = wpool;                             // [6][1536][512]
  short* projT= qkvT + 6ll*1536*512;               // [6][512][512]
  short* fc1T = projT + 6ll*512*512;               // [6][2048][512]
  short* fc2T = fc1T + 6ll*2048*512;               // [6][512][2048]
  short* outT = fc2T + 6ll*512*2048;               // [32000][512]

  // one-time weight convert+transpose (Wt[n][k] = bf16(W[k][n]))
  transpose_k<<<dim3(1536/64, 512/64, L_), 256, 0, stream>>>(qkv_w,  qkvT, 512, 1536);
  transpose_k<<<dim3( 512/64, 512/64, L_), 256, 0, stream>>>(proj_w, projT, 512, 512);
  transpose_k<<<dim3(2048/64, 512/64, L_), 256, 0, stream>>>(fc1_w,  fc1T, 512, 2048);
  transpose_k<<<dim3( 512/64,2048/64, L_), 256, 0, stream>>>(fc2_w,  fc2T, 2048, 512);
  transpose_k<<<dim3(V_/64,   512/64, 1 ), 256, 0, stream>>>(out_w,  outT, 512, V_);

  embed_k<<<M_, 128, 0, stream>>>(ids, tok, pos, x);

  for(int l = 0; l < L_; l++){
    ln_k<<<M_, 128, 0, stream>>>(x, ln1_g + l*E_, h);
    gemm_bf_k<128><<<(M_/128)*(1536/128), 256, 0, stream>>>(
        h, qkvT + (long long)l*1536*512, qkv_b + l*1536, nullptr, qkvb,
        M_, 1536, E_, 0, 1);
    fattn_k<<<(B_*H_) * (S_/64), 256, 0, stream>>>(qkvb, h);
    gemm_bf_k<64><<<(M_/128)*(512/64), 256, 0, stream>>>(
        h, projT + (long long)l*512*512, proj_b + l*E_, x, x,
        M_, E_, E_, 0, 0);
    ln_k<<<M_, 128, 0, stream>>>(x, ln2_g + l*E_, h);
    gemm_bf_k<128><<<(M_/128)*(2048/128), 256, 0, stream>>>(
        h, fc1T + (long long)l*2048*512, fc1_b + l*2048, nullptr, f1,
        M_, 2048, E_, 1, 1);
    gemm_bf_k<64><<<(M_/128)*(512/64), 256, 0, stream>>>(
        f1, fc2T + (long long)l*512*2048, fc2_b + l*E_, x, x,
        M_, E_, 2048, 0, 0);
  }

  ln_k<<<M_, 128, 0, stream>>>(x, lnf_g, h);
  gemm_bf_k<128><<<(M_/128)*(V_/128), 256, 0, stream>>>(
      h, outT, nullptr, nullptr, logits,
      M_, V_, E_, 0, 0);
}

// Round 5
// 2097.180 us; speedup vs baseline: 1.0170x; 1.0170x over previous
//
#include <hip/hip_runtime.h>
#include <math.h>

#define L_ 6
#define H_ 8
#define D_HD 64
#define E_ 512
#define V_ 32000
#define S_ 2048
#define B_ 2
#define M_ (B_*S_)   // 4096 rows

typedef float  floatx4 __attribute__((ext_vector_type(4)));
typedef short  shortx8 __attribute__((ext_vector_type(8)));
typedef short  shortx4 __attribute__((ext_vector_type(4)));

__device__ __forceinline__ short f2bf(float f){
  unsigned u = __builtin_bit_cast(unsigned, f);
  u += 0x7FFFu + ((u >> 16) & 1u);   // round-to-nearest-even
  return (short)(u >> 16);
}
__device__ __forceinline__ float bf2f(short s){
  unsigned u = ((unsigned)(unsigned short)s) << 16;
  return __builtin_bit_cast(float, u);
}
__device__ __forceinline__ float gelu_exact(float x){
  return 0.5f * x * (1.0f + erff(x * 0.70710678118654752440f));
}

typedef const __attribute__((address_space(1))) unsigned int* gas_p;
typedef __attribute__((address_space(3))) unsigned int* las_p;
__device__ __forceinline__ void gl16(const void* g, void* l){
  __builtin_amdgcn_global_load_lds((gas_p)g, (las_p)l, 16, 0, 0);
}

// XOR bank swizzle for 128B-row LDS tiles (attention K/V/P tiles)
__device__ __forceinline__ char* lds_at(void* base, int row, int colByte){
  return (char*)base + (((row << 7) + colByte) ^ ((row & 7) << 4));
}

// ---------------- embedding: x = tok_emb[id]/sqrt(E) + pos_emb[s] ----------
__global__ __launch_bounds__(128) void embed_k(const int* __restrict__ ids,
                                               const float* __restrict__ tok,
                                               const float* __restrict__ pos,
                                               float* __restrict__ x){
  int row = blockIdx.x;
  int s   = row & (S_ - 1);
  int id  = ids[row];
  const float4* te = (const float4*)(tok + (long long)id * E_);
  const float4* pe = (const float4*)(pos + (long long)s  * E_);
  float4 a = te[threadIdx.x];
  float4 b = pe[threadIdx.x];
  const float isq = 0.04419417382415922f;  // 1/sqrt(512)
  float4 o = { a.x*isq + b.x, a.y*isq + b.y, a.z*isq + b.z, a.w*isq + b.w };
  ((float4*)(x + (long long)row * E_))[threadIdx.x] = o;
}

// ---------------- LayerNorm, bf16 output -----------------------------------
__global__ __launch_bounds__(128) void ln_k(const float* __restrict__ x,
                                            const float* __restrict__ g,
                                            short* __restrict__ out){
  int row = blockIdx.x, tid = threadIdx.x;
  int lane = tid & 63, wid = tid >> 6;
  float4 v = ((const float4*)(x + (long long)row * E_))[tid];
  float s  = v.x + v.y + v.z + v.w;
  float sq = v.x*v.x + v.y*v.y + v.z*v.z + v.w*v.w;
  #pragma unroll
  for(int off = 32; off > 0; off >>= 1){
    s  += __shfl_xor(s,  off, 64);
    sq += __shfl_xor(sq, off, 64);
  }
  __shared__ float ss[2], sqs[2];
  if(lane == 0){ ss[wid] = s; sqs[wid] = sq; }
  __syncthreads();
  s = ss[0] + ss[1]; sq = sqs[0] + sqs[1];
  float mu  = s * (1.0f / E_);
  float var = sq * (1.0f / E_) - mu * mu;
  float rs  = rsqrtf(var + 1e-6f);
  float4 gv = ((const float4*)g)[tid];
  shortx4 ob = { f2bf((v.x-mu)*rs*gv.x), f2bf((v.y-mu)*rs*gv.y),
                 f2bf((v.z-mu)*rs*gv.z), f2bf((v.w-mu)*rs*gv.w) };
  ((shortx4*)(out + (long long)row * E_))[tid] = ob;
}

// ---------------- weight transpose+convert: Wt[n][k] = bf16(W[k][n]) -------
__global__ __launch_bounds__(256) void transpose_k(const float* __restrict__ W,
                                                   short* __restrict__ Wt,
                                                   int K, int N){
  __shared__ short t[64][68];
  int tid = threadIdx.x;
  int r16 = tid >> 4, c4 = (tid & 15) * 4;
  long long base = (long long)blockIdx.z * K * N;
  int n0 = blockIdx.x * 64, k0 = blockIdx.y * 64;
  #pragma unroll
  for(int ph = 0; ph < 4; ph++){
    int row = ph*16 + r16;
    float4 v = *(const float4*)(W + base + (long long)(k0+row)*N + n0 + c4);
    t[row][c4+0]=f2bf(v.x); t[row][c4+1]=f2bf(v.y);
    t[row][c4+2]=f2bf(v.z); t[row][c4+3]=f2bf(v.w);
  }
  __syncthreads();
  #pragma unroll
  for(int ph = 0; ph < 4; ph++){
    int orow = ph*16 + r16;   // n-local
    shortx4 o = { t[c4+0][orow], t[c4+1][orow], t[c4+2][orow], t[c4+3][orow] };
    *(shortx4*)(Wt + base + (long long)(n0+orow)*K + k0 + c4) = o;
  }
}

// ---------------- MFMA GEMM, bf16 A x bf16 Wt^T, 128xBN tile, BK=32 --------
// (reverted to the round-3 structure: BK=64 regressed — 1.6e7 bank-conflict
//  cycles + 32KB LDS occupancy loss). ntst: non-temporal fp32 store for
// streaming outputs that are never re-read (logits) — keeps W L2/L3-hot.
template<int BN>
__global__ __launch_bounds__(256) void gemm_bf_k(const short* __restrict__ A,
                                                 const short* __restrict__ Wt,
                                                 const float* __restrict__ bias,
                                                 const float* __restrict__ res,
                                                 void* __restrict__ Cout,
                                                 int M, int N, int K,
                                                 int act, int outbf, int ntst){
  constexpr int NT = BN / 32;       // n-fragments per wave
  __shared__ short As[4096];        // [128][32] bf16, swizzled
  __shared__ short Bs[BN*32];       // [BN][32]  bf16, swizzled
  int tid = threadIdx.x;
  int wave = tid >> 6, lane = tid & 63, quad = lane >> 4, l16 = lane & 15;
  int wr = wave >> 1, wc = wave & 1;

  int MT  = M >> 7;
  int nwg = gridDim.x, bid = blockIdx.x;
  int nb  = bid;
  if((nwg & 7) == 0) nb = (bid & 7) * (nwg >> 3) + (bid >> 3);
  long long m0 = (long long)(nb % MT) << 7;
  long long n0 = (long long)(nb / MT) * BN;

  // staging: lds byte tid*16 (+4096 for issue 1) <-> row=tid>>2, slot=tid&3;
  // source chunk gq = slot ^ f(row), f(row)=(row&3)^((row>>2)&3)
  int rs = tid >> 2;
  int gq = (tid & 3) ^ ((tid >> 2) & 3) ^ ((tid >> 4) & 3);
  const short* a0 = A  + (m0 + rs)      * (long long)K + gq * 8;
  const short* a1 = A  + (m0 + rs + 64) * (long long)K + gq * 8;
  const short* b0 = Wt + (n0 + rs)      * (long long)K + gq * 8;
  const short* b1 = (BN == 128) ? Wt + (n0 + rs + 64) * (long long)K + gq * 8 : nullptr;
  char* dA = (char*)As + wave * 1024;
  char* dB = (char*)Bs + wave * 1024;

  int aoff[4], boff[NT];
  #pragma unroll
  for(int t = 0; t < 4; t++){
    int ra = wr*64 + t*16 + l16;
    aoff[t] = ra*64 + ((quad ^ (ra & 3) ^ ((ra >> 2) & 3)) << 4);
  }
  #pragma unroll
  for(int t = 0; t < NT; t++){
    int rb = wc*(BN/2) + t*16 + l16;
    boff[t] = rb*64 + ((quad ^ (rb & 3) ^ ((rb >> 2) & 3)) << 4);
  }

  floatx4 acc[4][NT];
  #pragma unroll
  for(int i = 0; i < 4; i++)
    #pragma unroll
    for(int j = 0; j < NT; j++)
      acc[i][j] = (floatx4){0.f, 0.f, 0.f, 0.f};

  for(int k0 = 0; k0 < K; k0 += 32){
    gl16(a0, dA);        gl16(a1, dA + 4096);
    gl16(b0, dB);
    if(BN == 128) gl16(b1, dB + 4096);
    a0 += 32; a1 += 32; b0 += 32;
    if(BN == 128) b1 += 32;
    __syncthreads();
    shortx8 af[4], bfr[NT];
    #pragma unroll
    for(int t = 0; t < 4; t++)
      af[t]  = *(const shortx8*)((const char*)As + aoff[t]);
    #pragma unroll
    for(int t = 0; t < NT; t++)
      bfr[t] = *(const shortx8*)((const char*)Bs + boff[t]);
    #pragma unroll
    for(int i = 0; i < 4; i++)
      #pragma unroll
      for(int j = 0; j < NT; j++)
        acc[i][j] = __builtin_amdgcn_mfma_f32_16x16x32_bf16(af[i], bfr[j], acc[i][j], 0, 0, 0);
    __syncthreads();
  }

  #pragma unroll
  for(int i = 0; i < 4; i++){
    #pragma unroll
    for(int r = 0; r < 4; r++){
      long long row = m0 + wr*64 + i*16 + quad*4 + r;
      #pragma unroll
      for(int j = 0; j < NT; j++){
        long long col = n0 + wc*(BN/2) + j*16 + l16;
        float v = acc[i][j][r];
        if(bias) v += bias[col];
        if(act)  v = gelu_exact(v);
        if(res)  v += res[row * N + col];
        if(outbf)     ((short*)Cout)[row * N + col] = f2bf(v);
        else if(ntst) __builtin_nontemporal_store(v, (float*)Cout + row * N + col);
        else          ((float*)Cout)[row * N + col] = v;
      }
    }
  }
}

// ---------------- flash attention, bf16 qkv input, MFMA 16x16x32 -----------
// Raw-unit running max (scale folded into exp FMA), defer-rescale (T13,
// raw threshold 64 -> P <= e^8), setprio around MFMA clusters (T5).
__global__ __launch_bounds__(256) void fattn_k(const short* __restrict__ qkv,
                                               short* __restrict__ out){
  __shared__ short Ks[64*64];      // K tile,  [k][d] bf16, swizzled   8KB
  __shared__ short Vt[64*64];      // V tile,  [d][k] bf16, swizzled   8KB
  __shared__ short Ps[4*16*64];    // per-wave P, [q16][k64] bf16      8KB
  int tid = threadIdx.x, wave = tid >> 6, lane = tid & 63;
  int quad = lane >> 4, l16 = lane & 15;
  int bh = blockIdx.x & 15;
  int qt = 31 - (blockIdx.x >> 4);   // heavy q-tiles dispatch first
  int b = bh >> 3, h = bh & 7;
  int q0 = qt * 64;

  const short* base = qkv + (long long)b * S_ * 1536;
  const short* Qb = base + h*64;
  const short* Kb = base + 512  + h*64;
  const short* Vb = base + 1024 + h*64;

  shortx8 qf[2];
  {
    const short* qp = Qb + (long long)(q0 + 16*wave + l16) * 1536 + quad*8;
    qf[0] = *(const shortx8*)(qp);
    qf[1] = *(const shortx8*)(qp + 32);
  }

  float m_s = -1e30f, l_s = 0.f;     // m_s in RAW score units
  floatx4 acc_o[4] = {{0,0,0,0},{0,0,0,0},{0,0,0,0},{0,0,0,0}};

  int krow   = wave*8 + (lane >> 3);
  int kchunk = (lane & 7) ^ (krow & 7);
  const short* kA = Kb + (long long)krow * 1536 + kchunk * 8;
  char* dK0 = (char*)Ks + wave * 1024;
  char* dK1 = dK0 + 4096;

  int vk4 = (tid >> 4) * 4, vd4 = (tid & 15) * 4;
  const short* vp = Vb + (long long)vk4 * 1536 + vd4;
  char* pbase = (char*)Ps + wave * 2048;

  for(int k0 = 0; k0 <= q0; k0 += 64){
    gl16(kA, dK0);
    gl16(kA + 32*1536, dK1);
    {
      shortx4 r0 = *(const shortx4*)(vp);
      shortx4 r1 = *(const shortx4*)(vp + 1536);
      shortx4 r2 = *(const shortx4*)(vp + 2*1536);
      shortx4 r3 = *(const shortx4*)(vp + 3*1536);
      shortx4 v0 = {r0[0], r1[0], r2[0], r3[0]};
      shortx4 v1 = {r0[1], r1[1], r2[1], r3[1]};
      shortx4 v2 = {r0[2], r1[2], r2[2], r3[2]};
      shortx4 v3 = {r0[3], r1[3], r2[3], r3[3]};
      *(shortx4*)lds_at(Vt, vd4+0, vk4*2) = v0;
      *(shortx4*)lds_at(Vt, vd4+1, vk4*2) = v1;
      *(shortx4*)lds_at(Vt, vd4+2, vk4*2) = v2;
      *(shortx4*)lds_at(Vt, vd4+3, vk4*2) = v3;
    }
    kA += 64*1536; vp += 64*1536;
    __syncthreads();

    floatx4 s[4] = {{0,0,0,0},{0,0,0,0},{0,0,0,0},{0,0,0,0}};
    __builtin_amdgcn_s_setprio(1);
    #pragma unroll
    for(int ks2 = 0; ks2 < 2; ks2++){
      #pragma unroll
      for(int t = 0; t < 4; t++){
        shortx8 kf = *(const shortx8*)lds_at(Ks, 16*t + l16, quad*16 + ks2*64);
        s[t] = __builtin_amdgcn_mfma_f32_16x16x32_bf16(kf, qf[ks2], s[t], 0, 0, 0);
      }
    }
    __builtin_amdgcn_s_setprio(0);

    if(k0 == q0){
      int q = q0 + 16*wave + l16;
      #pragma unroll
      for(int t = 0; t < 4; t++){
        #pragma unroll
        for(int r = 0; r < 4; r++){
          int k = k0 + 16*t + quad*4 + r;
          if(k > q) s[t][r] = -1e30f;
        }
      }
    }

    // ---- row max (raw units) ----
    float mloc = -1e30f;
    #pragma unroll
    for(int t = 0; t < 4; t++)
      mloc = fmaxf(mloc, fmaxf(fmaxf(s[t][0], s[t][1]), fmaxf(s[t][2], s[t][3])));
    mloc = fmaxf(mloc, __shfl_xor(mloc, 16, 64));
    mloc = fmaxf(mloc, __shfl_xor(mloc, 32, 64));

    // ---- defer-rescale: only rescale when max grows by >64 raw (= 8 scaled)
    if(!__all(mloc - m_s <= 64.0f)){
      float mnew  = fmaxf(m_s, mloc);
      float sc    = __expf((m_s - mnew) * 0.125f);   // 0 on first tile
      l_s *= sc;
      #pragma unroll
      for(int r = 0; r < 4; r++){
        float scr = __shfl(sc, (lane & 48) | (quad*4 + r), 64);
        #pragma unroll
        for(int t = 0; t < 4; t++) acc_o[t][r] *= scr;
      }
      m_s = mnew;
    }

    float nm = -0.125f * m_s;
    float sumloc = 0.f;
    shortx4 pw[4];
    #pragma unroll
    for(int t = 0; t < 4; t++){
      #pragma unroll
      for(int r = 0; r < 4; r++){
        float e = __expf(fmaf(s[t][r], 0.125f, nm));
        short pb = f2bf(e);
        pw[t][r] = pb;
        sumloc += bf2f(pb);
      }
    }
    sumloc += __shfl_xor(sumloc, 16, 64);
    sumloc += __shfl_xor(sumloc, 32, 64);
    l_s += sumloc;

    #pragma unroll
    for(int t = 0; t < 4; t++)
      *(shortx4*)lds_at(pbase, l16, 32*t + 8*quad) = pw[t];
    asm volatile("" ::: "memory");

    __builtin_amdgcn_s_setprio(1);
    #pragma unroll
    for(int ks2 = 0; ks2 < 2; ks2++){
      shortx8 pf = *(const shortx8*)lds_at(pbase, l16, quad*16 + ks2*64);
      #pragma unroll
      for(int t = 0; t < 4; t++){
        shortx8 vf = *(const shortx8*)lds_at(Vt, 16*t + l16, quad*16 + ks2*64);
        acc_o[t] = __builtin_amdgcn_mfma_f32_16x16x32_bf16(pf, vf, acc_o[t], 0, 0, 0);
      }
    }
    __builtin_amdgcn_s_setprio(0);
    __syncthreads();
  }

  #pragma unroll
  for(int r = 0; r < 4; r++){
    float li  = __shfl(l_s, (lane & 48) | (quad*4 + r), 64);
    float inv = 1.0f / li;
    int qrow = q0 + 16*wave + quad*4 + r;
    short* op = out + ((long long)(b*S_ + qrow)) * E_ + h*64 + l16;
    #pragma unroll
    for(int t = 0; t < 4; t++) op[16*t] = f2bf(acc_o[t][r] * inv);
  }
}

// ---------------------------------------------------------------------------
extern "C" void kernel_launch(void* const* d_in, const int* in_sizes, int n_in,
                              void* d_out, int out_size, void* d_ws, size_t ws_size,
                              hipStream_t stream){
  const int*   ids    = (const int*)d_in[0];
  const float* tok    = (const float*)d_in[1];
  const float* pos    = (const float*)d_in[2];
  const float* qkv_w  = (const float*)d_in[3];
  const float* qkv_b  = (const float*)d_in[4];
  const float* proj_w = (const float*)d_in[5];
  const float* proj_b = (const float*)d_in[6];
  const float* fc1_w  = (const float*)d_in[7];
  const float* fc1_b  = (const float*)d_in[8];
  const float* fc2_w  = (const float*)d_in[9];
  const float* fc2_b  = (const float*)d_in[10];
  const float* ln1_g  = (const float*)d_in[11];
  const float* ln2_g  = (const float*)d_in[12];
  const float* lnf_g  = (const float*)d_in[13];
  const float* out_w  = (const float*)d_in[14];
  float* logits = (float*)d_out;

  char* w = (char*)d_ws;
  float* x    = (float*)(w);                       // [4096,512]  fp32   8 MB
  short* h    = (short*)(w + (8ll  << 20));        // [4096,512]  bf16   4 MB
  short* qkvb = (short*)(w + (12ll << 20));        // [4096,1536] bf16  12 MB
  short* f1   = (short*)(w + (24ll << 20));        // [4096,2048] bf16  16 MB
  short* wpool= (short*)(w + (40ll << 20));        // bf16 Wt pool    70.6 MB
  short* qkvT = wpool;                             // [6][1536][512]
  short* projT= qkvT + 6ll*1536*512;               // [6][512][512]
  short* fc1T = projT + 6ll*512*512;               // [6][2048][512]
  short* fc2T = fc1T + 6ll*2048*512;               // [6][512][2048]
  short* outT = fc2T + 6ll*512*2048;               // [32000][512]

  // one-time weight convert+transpose (Wt[n][k] = bf16(W[k][n]))
  transpose_k<<<dim3(1536/64, 512/64, L_), 256, 0, stream>>>(qkv_w,  qkvT, 512, 1536);
  transpose_k<<<dim3( 512/64, 512/64, L_), 256, 0, stream>>>(proj_w, projT, 512, 512);
  transpose_k<<<dim3(2048/64, 512/64, L_), 256, 0, stream>>>(fc1_w,  fc1T, 512, 2048);
  transpose_k<<<dim3( 512/64,2048/64, L_), 256, 0, stream>>>(fc2_w,  fc2T, 2048, 512);
  transpose_k<<<dim3(V_/64,   512/64, 1 ), 256, 0, stream>>>(out_w,  outT, 512, V_);

  embed_k<<<M_, 128, 0, stream>>>(ids, tok, pos, x);

  for(int l = 0; l < L_; l++){
    ln_k<<<M_, 128, 0, stream>>>(x, ln1_g + l*E_, h);
    gemm_bf_k<128><<<(M_/128)*(1536/128), 256, 0, stream>>>(
        h, qkvT + (long long)l*1536*512, qkv_b + l*1536, nullptr, qkvb,
        M_, 1536, E_, 0, 1, 0);
    fattn_k<<<(B_*H_) * (S_/64), 256, 0, stream>>>(qkvb, h);
    gemm_bf_k<64><<<(M_/128)*(512/64), 256, 0, stream>>>(
        h, projT + (long long)l*512*512, proj_b + l*E_, x, x,
        M_, E_, E_, 0, 0, 0);
    ln_k<<<M_, 128, 0, stream>>>(x, ln2_g + l*E_, h);
    gemm_bf_k<128><<<(M_/128)*(2048/128), 256, 0, stream>>>(
        h, fc1T + (long long)l*2048*512, fc1_b + l*2048, nullptr, f1,
        M_, 2048, E_, 1, 1, 0);
    gemm_bf_k<64><<<(M_/128)*(512/64), 256, 0, stream>>>(
        f1, fc2T + (long long)l*512*2048, fc2_b + l*E_, x, x,
        M_, E_, 2048, 0, 0, 0);
  }

  ln_k<<<M_, 128, 0, stream>>>(x, lnf_g, h);
  gemm_bf_k<128><<<(M_/128)*(V_/128), 256, 0, stream>>>(
      h, outT, nullptr, nullptr, logits,
      M_, V_, E_, 0, 0, 1);
}

// Round 6
// 2032.371 us; speedup vs baseline: 1.0494x; 1.0319x over previous
//
#include <hip/hip_runtime.h>
#include <math.h>

#define L_ 6
#define H_ 8
#define D_HD 64
#define E_ 512
#define V_ 32000
#define S_ 2048
#define B_ 2
#define M_ (B_*S_)   // 4096 rows

typedef float  floatx4 __attribute__((ext_vector_type(4)));
typedef short  shortx8 __attribute__((ext_vector_type(8)));
typedef short  shortx4 __attribute__((ext_vector_type(4)));

__device__ __forceinline__ short f2bf(float f){
  unsigned u = __builtin_bit_cast(unsigned, f);
  u += 0x7FFFu + ((u >> 16) & 1u);   // round-to-nearest-even
  return (short)(u >> 16);
}
__device__ __forceinline__ float bf2f(short s){
  unsigned u = ((unsigned)(unsigned short)s) << 16;
  return __builtin_bit_cast(float, u);
}
__device__ __forceinline__ float gelu_exact(float x){
  return 0.5f * x * (1.0f + erff(x * 0.70710678118654752440f));
}

typedef const __attribute__((address_space(1))) unsigned int* gas_p;
typedef __attribute__((address_space(3))) unsigned int* las_p;
__device__ __forceinline__ void gl16(const void* g, void* l){
  __builtin_amdgcn_global_load_lds((gas_p)g, (las_p)l, 16, 0, 0);
}

// pipeline barrier: counted-drain + raw barrier (bypasses __syncthreads'
// conservative early drain; one per iteration — T3 minimum 2-phase)
#define PIPE_BARRIER() asm volatile("s_waitcnt vmcnt(0) lgkmcnt(0)\n\ts_barrier" ::: "memory")

// XOR bank swizzle for 128B-row LDS tiles (attention K/V/P tiles)
__device__ __forceinline__ char* lds_at(void* base, int row, int colByte){
  return (char*)base + (((row << 7) + colByte) ^ ((row & 7) << 4));
}

// ---------------- embedding: x = tok_emb[id]/sqrt(E) + pos_emb[s] ----------
__global__ __launch_bounds__(128) void embed_k(const int* __restrict__ ids,
                                               const float* __restrict__ tok,
                                               const float* __restrict__ pos,
                                               float* __restrict__ x){
  int row = blockIdx.x;
  int s   = row & (S_ - 1);
  int id  = ids[row];
  const float4* te = (const float4*)(tok + (long long)id * E_);
  const float4* pe = (const float4*)(pos + (long long)s  * E_);
  float4 a = te[threadIdx.x];
  float4 b = pe[threadIdx.x];
  const float isq = 0.04419417382415922f;  // 1/sqrt(512)
  float4 o = { a.x*isq + b.x, a.y*isq + b.y, a.z*isq + b.z, a.w*isq + b.w };
  ((float4*)(x + (long long)row * E_))[threadIdx.x] = o;
}

// ---------------- LayerNorm, bf16 output -----------------------------------
__global__ __launch_bounds__(128) void ln_k(const float* __restrict__ x,
                                            const float* __restrict__ g,
                                            short* __restrict__ out){
  int row = blockIdx.x, tid = threadIdx.x;
  int lane = tid & 63, wid = tid >> 6;
  float4 v = ((const float4*)(x + (long long)row * E_))[tid];
  float s  = v.x + v.y + v.z + v.w;
  float sq = v.x*v.x + v.y*v.y + v.z*v.z + v.w*v.w;
  #pragma unroll
  for(int off = 32; off > 0; off >>= 1){
    s  += __shfl_xor(s,  off, 64);
    sq += __shfl_xor(sq, off, 64);
  }
  __shared__ float ss[2], sqs[2];
  if(lane == 0){ ss[wid] = s; sqs[wid] = sq; }
  __syncthreads();
  s = ss[0] + ss[1]; sq = sqs[0] + sqs[1];
  float mu  = s * (1.0f / E_);
  float var = sq * (1.0f / E_) - mu * mu;
  float rs  = rsqrtf(var + 1e-6f);
  float4 gv = ((const float4*)g)[tid];
  shortx4 ob = { f2bf((v.x-mu)*rs*gv.x), f2bf((v.y-mu)*rs*gv.y),
                 f2bf((v.z-mu)*rs*gv.z), f2bf((v.w-mu)*rs*gv.w) };
  ((shortx4*)(out + (long long)row * E_))[tid] = ob;
}

// ---------------- weight transpose+convert: Wt[n][k] = bf16(W[k][n]) -------
__global__ __launch_bounds__(256) void transpose_k(const float* __restrict__ W,
                                                   short* __restrict__ Wt,
                                                   int K, int N){
  __shared__ short t[64][68];
  int tid = threadIdx.x;
  int r16 = tid >> 4, c4 = (tid & 15) * 4;
  long long base = (long long)blockIdx.z * K * N;
  int n0 = blockIdx.x * 64, k0 = blockIdx.y * 64;
  #pragma unroll
  for(int ph = 0; ph < 4; ph++){
    int row = ph*16 + r16;
    float4 v = *(const float4*)(W + base + (long long)(k0+row)*N + n0 + c4);
    t[row][c4+0]=f2bf(v.x); t[row][c4+1]=f2bf(v.y);
    t[row][c4+2]=f2bf(v.z); t[row][c4+3]=f2bf(v.w);
  }
  __syncthreads();
  #pragma unroll
  for(int ph = 0; ph < 4; ph++){
    int orow = ph*16 + r16;   // n-local
    shortx4 o = { t[c4+0][orow], t[c4+1][orow], t[c4+2][orow], t[c4+3][orow] };
    *(shortx4*)(Wt + base + (long long)(n0+orow)*K + k0 + c4) = o;
  }
}

// ---------------- MFMA GEMM, bf16 A x bf16 Wt^T, 128xBN tile, BK=32 --------
// Double-buffered LDS + stage-ahead (T3 minimum 2-phase): iteration t issues
// gl16 for tile t+1 into buf[p^1] BEFORE computing tile t from buf[p]; one
// PIPE_BARRIER per iteration. Proven <=2-way swizzle layout kept per buffer.
template<int BN>
__global__ __launch_bounds__(256) void gemm_bf_k(const short* __restrict__ A,
                                                 const short* __restrict__ Wt,
                                                 const float* __restrict__ bias,
                                                 const float* __restrict__ res,
                                                 void* __restrict__ Cout,
                                                 int M, int N, int K,
                                                 int act, int outbf, int ntst){
  constexpr int NT = BN / 32;       // n-fragments per wave
  __shared__ short As[2][4096];     // [buf][128][32] bf16, swizzled
  __shared__ short Bs[2][BN*32];    // [buf][BN][32]  bf16, swizzled
  int tid = threadIdx.x;
  int wave = tid >> 6, lane = tid & 63, quad = lane >> 4, l16 = lane & 15;
  int wr = wave >> 1, wc = wave & 1;

  int MT  = M >> 7;
  int nwg = gridDim.x, bid = blockIdx.x;
  int nb  = bid;
  if((nwg & 7) == 0) nb = (bid & 7) * (nwg >> 3) + (bid >> 3);
  long long m0 = (long long)(nb % MT) << 7;
  long long n0 = (long long)(nb / MT) * BN;

  // staging: lds byte tid*16 (+4096 for issue 1) <-> row=tid>>2, slot=tid&3;
  // source chunk gq = slot ^ f(row), f(row)=(row&3)^((row>>2)&3)
  int rs = tid >> 2;
  int gq = (tid & 3) ^ ((tid >> 2) & 3) ^ ((tid >> 4) & 3);
  const short* a0 = A  + (m0 + rs)      * (long long)K + gq * 8;
  const short* a1 = A  + (m0 + rs + 64) * (long long)K + gq * 8;
  const short* b0 = Wt + (n0 + rs)      * (long long)K + gq * 8;
  const short* b1 = (BN == 128) ? Wt + (n0 + rs + 64) * (long long)K + gq * 8 : nullptr;

  auto STAGE = [&](int buf){
    char* dA = (char*)As[buf] + wave * 1024;
    char* dB = (char*)Bs[buf] + wave * 1024;
    gl16(a0, dA);  gl16(a1, dA + 4096);
    gl16(b0, dB);
    if(BN == 128) gl16(b1, dB + 4096);
    a0 += 32; a1 += 32; b0 += 32;
    if(BN == 128) b1 += 32;
  };

  int aoff[4], boff[NT];
  #pragma unroll
  for(int t = 0; t < 4; t++){
    int ra = wr*64 + t*16 + l16;
    aoff[t] = ra*64 + ((quad ^ (ra & 3) ^ ((ra >> 2) & 3)) << 4);
  }
  #pragma unroll
  for(int t = 0; t < NT; t++){
    int rb = wc*(BN/2) + t*16 + l16;
    boff[t] = rb*64 + ((quad ^ (rb & 3) ^ ((rb >> 2) & 3)) << 4);
  }

  floatx4 acc[4][NT];
  #pragma unroll
  for(int i = 0; i < 4; i++)
    #pragma unroll
    for(int j = 0; j < NT; j++)
      acc[i][j] = (floatx4){0.f, 0.f, 0.f, 0.f};

  STAGE(0);
  PIPE_BARRIER();
  int nk = K >> 5, p = 0;
  for(int kk = 0; kk < nk; ++kk){
    if(kk + 1 < nk) STAGE(p ^ 1);          // prefetch next tile (overlaps MFMA)
    shortx8 af[4], bfr[NT];
    #pragma unroll
    for(int t = 0; t < 4; t++)
      af[t]  = *(const shortx8*)((const char*)As[p] + aoff[t]);
    #pragma unroll
    for(int t = 0; t < NT; t++)
      bfr[t] = *(const shortx8*)((const char*)Bs[p] + boff[t]);
    #pragma unroll
    for(int i = 0; i < 4; i++)
      #pragma unroll
      for(int j = 0; j < NT; j++)
        acc[i][j] = __builtin_amdgcn_mfma_f32_16x16x32_bf16(af[i], bfr[j], acc[i][j], 0, 0, 0);
    PIPE_BARRIER();
    p ^= 1;
  }

  #pragma unroll
  for(int i = 0; i < 4; i++){
    #pragma unroll
    for(int r = 0; r < 4; r++){
      long long row = m0 + wr*64 + i*16 + quad*4 + r;
      #pragma unroll
      for(int j = 0; j < NT; j++){
        long long col = n0 + wc*(BN/2) + j*16 + l16;
        float v = acc[i][j][r];
        if(bias) v += bias[col];
        if(act)  v = gelu_exact(v);
        if(res)  v += res[row * N + col];
        if(outbf)     ((short*)Cout)[row * N + col] = f2bf(v);
        else if(ntst) __builtin_nontemporal_store(v, (float*)Cout + row * N + col);
        else          ((float*)Cout)[row * N + col] = v;
      }
    }
  }
}

// ---------------- flash attention, bf16 qkv, double-buffered pipeline ------
// Iteration t: issue gl16 K(t+1) + global V(t+1)->regs (T14 issue-early),
// compute tile t (QK mfma / online softmax / PV mfma), then vmcnt-wait +
// ds_write V(t+1) (write-late), one PIPE_BARRIER. 40 KB LDS.
__global__ __launch_bounds__(256) void fattn_k(const short* __restrict__ qkv,
                                               short* __restrict__ out){
  __shared__ short Ks[2][4096];    // K tiles, [k][d] bf16, swizzled  2x8KB
  __shared__ short Vt[2][4096];    // V tiles, [d][k] bf16, swizzled  2x8KB
  __shared__ short Ps[4][1024];    // per-wave P, [q16][k64] bf16       8KB
  int tid = threadIdx.x, wave = tid >> 6, lane = tid & 63;
  int quad = lane >> 4, l16 = lane & 15;
  int bh = blockIdx.x & 15;
  int qt = 31 - (blockIdx.x >> 4);   // heavy q-tiles dispatch first
  int b = bh >> 3, h = bh & 7;
  int q0 = qt * 64;

  const short* base = qkv + (long long)b * S_ * 1536;
  const short* Qb = base + h*64;
  const short* Kb = base + 512  + h*64;
  const short* Vb = base + 1024 + h*64;

  shortx8 qf[2];
  {
    const short* qp = Qb + (long long)(q0 + 16*wave + l16) * 1536 + quad*8;
    qf[0] = *(const shortx8*)(qp);
    qf[1] = *(const shortx8*)(qp + 32);
  }

  float m_s = -1e30f, l_s = 0.f;     // m_s in RAW score units
  floatx4 acc_o[4] = {{0,0,0,0},{0,0,0,0},{0,0,0,0},{0,0,0,0}};

  int krow   = wave*8 + (lane >> 3);
  int kchunk = (lane & 7) ^ (krow & 7);
  const short* kA = Kb + (long long)krow * 1536 + kchunk * 8;

  int vk4 = (tid >> 4) * 4, vd4 = (tid & 15) * 4;
  const short* vp = Vb + (long long)vk4 * 1536 + vd4;
  char* pbase = (char*)Ps[wave];

  shortx4 r0, r1, r2, r3;            // in-flight V rows (T14)
  auto STAGE_K = [&](int buf){
    char* d = (char*)Ks[buf] + wave * 1024;
    gl16(kA, d);
    gl16(kA + 32*1536, d + 4096);
  };
  auto VLOAD = [&](){
    r0 = *(const shortx4*)(vp);
    r1 = *(const shortx4*)(vp + 1536);
    r2 = *(const shortx4*)(vp + 2*1536);
    r3 = *(const shortx4*)(vp + 3*1536);
  };
  auto VWRITE = [&](int buf){
    shortx4 v0 = {r0[0], r1[0], r2[0], r3[0]};
    shortx4 v1 = {r0[1], r1[1], r2[1], r3[1]};
    shortx4 v2 = {r0[2], r1[2], r2[2], r3[2]};
    shortx4 v3 = {r0[3], r1[3], r2[3], r3[3]};
    *(shortx4*)lds_at(Vt[buf], vd4+0, vk4*2) = v0;
    *(shortx4*)lds_at(Vt[buf], vd4+1, vk4*2) = v1;
    *(shortx4*)lds_at(Vt[buf], vd4+2, vk4*2) = v2;
    *(shortx4*)lds_at(Vt[buf], vd4+3, vk4*2) = v3;
  };

  // prologue: stage tile 0 into buffer 0
  STAGE_K(0);
  VLOAD();
  asm volatile("s_waitcnt vmcnt(0)" ::: "memory");
  VWRITE(0);
  kA += 64*1536; vp += 64*1536;
  PIPE_BARRIER();
  int p = 0;

  for(int k0 = 0; k0 <= q0; k0 += 64){
    bool has_next = (k0 + 64 <= q0);
    if(has_next){                      // issue next tile's loads early
      STAGE_K(p ^ 1);
      VLOAD();
      kA += 64*1536; vp += 64*1536;
    }

    // ---- QK^T on current buffer ----
    floatx4 s[4] = {{0,0,0,0},{0,0,0,0},{0,0,0,0},{0,0,0,0}};
    __builtin_amdgcn_s_setprio(1);
    #pragma unroll
    for(int ks2 = 0; ks2 < 2; ks2++){
      #pragma unroll
      for(int t = 0; t < 4; t++){
        shortx8 kf = *(const shortx8*)lds_at(Ks[p], 16*t + l16, quad*16 + ks2*64);
        s[t] = __builtin_amdgcn_mfma_f32_16x16x32_bf16(kf, qf[ks2], s[t], 0, 0, 0);
      }
    }
    __builtin_amdgcn_s_setprio(0);

    if(k0 == q0){
      int q = q0 + 16*wave + l16;
      #pragma unroll
      for(int t = 0; t < 4; t++){
        #pragma unroll
        for(int r = 0; r < 4; r++){
          int k = k0 + 16*t + quad*4 + r;
          if(k > q) s[t][r] = -1e30f;
        }
      }
    }

    // ---- row max (raw units) ----
    float mloc = -1e30f;
    #pragma unroll
    for(int t = 0; t < 4; t++)
      mloc = fmaxf(mloc, fmaxf(fmaxf(s[t][0], s[t][1]), fmaxf(s[t][2], s[t][3])));
    mloc = fmaxf(mloc, __shfl_xor(mloc, 16, 64));
    mloc = fmaxf(mloc, __shfl_xor(mloc, 32, 64));

    // ---- defer-rescale (T13): raw threshold 64 (= 8 scaled) ----
    if(!__all(mloc - m_s <= 64.0f)){
      float mnew  = fmaxf(m_s, mloc);
      float sc    = __expf((m_s - mnew) * 0.125f);   // 0 on first tile
      l_s *= sc;
      #pragma unroll
      for(int r = 0; r < 4; r++){
        float scr = __shfl(sc, (lane & 48) | (quad*4 + r), 64);
        #pragma unroll
        for(int t = 0; t < 4; t++) acc_o[t][r] *= scr;
      }
      m_s = mnew;
    }

    float nm = -0.125f * m_s;
    float sumloc = 0.f;
    shortx4 pw[4];
    #pragma unroll
    for(int t = 0; t < 4; t++){
      #pragma unroll
      for(int r = 0; r < 4; r++){
        float e = __expf(fmaf(s[t][r], 0.125f, nm));
        short pb = f2bf(e);
        pw[t][r] = pb;
        sumloc += bf2f(pb);
      }
    }
    sumloc += __shfl_xor(sumloc, 16, 64);
    sumloc += __shfl_xor(sumloc, 32, 64);
    l_s += sumloc;

    #pragma unroll
    for(int t = 0; t < 4; t++)
      *(shortx4*)lds_at(pbase, l16, 32*t + 8*quad) = pw[t];
    asm volatile("" ::: "memory");   // pin P writes before same-wave P reads

    // ---- O += P @ V (current buffer) ----
    __builtin_amdgcn_s_setprio(1);
    #pragma unroll
    for(int ks2 = 0; ks2 < 2; ks2++){
      shortx8 pf = *(const shortx8*)lds_at(pbase, l16, quad*16 + ks2*64);
      #pragma unroll
      for(int t = 0; t < 4; t++){
        shortx8 vf = *(const shortx8*)lds_at(Vt[p], 16*t + l16, quad*16 + ks2*64);
        acc_o[t] = __builtin_amdgcn_mfma_f32_16x16x32_bf16(pf, vf, acc_o[t], 0, 0, 0);
      }
    }
    __builtin_amdgcn_s_setprio(0);

    if(has_next){                      // write-late V into next buffer
      asm volatile("s_waitcnt vmcnt(0)" ::: "memory");
      VWRITE(p ^ 1);
    }
    PIPE_BARRIER();
    p ^= 1;
  }

  #pragma unroll
  for(int r = 0; r < 4; r++){
    float li  = __shfl(l_s, (lane & 48) | (quad*4 + r), 64);
    float inv = 1.0f / li;
    int qrow = q0 + 16*wave + quad*4 + r;
    short* op = out + ((long long)(b*S_ + qrow)) * E_ + h*64 + l16;
    #pragma unroll
    for(int t = 0; t < 4; t++) op[16*t] = f2bf(acc_o[t][r] * inv);
  }
}

// ---------------------------------------------------------------------------
extern "C" void kernel_launch(void* const* d_in, const int* in_sizes, int n_in,
                              void* d_out, int out_size, void* d_ws, size_t ws_size,
                              hipStream_t stream){
  const int*   ids    = (const int*)d_in[0];
  const float* tok    = (const float*)d_in[1];
  const float* pos    = (const float*)d_in[2];
  const float* qkv_w  = (const float*)d_in[3];
  const float* qkv_b  = (const float*)d_in[4];
  const float* proj_w = (const float*)d_in[5];
  const float* proj_b = (const float*)d_in[6];
  const float* fc1_w  = (const float*)d_in[7];
  const float* fc1_b  = (const float*)d_in[8];
  const float* fc2_w  = (const float*)d_in[9];
  const float* fc2_b  = (const float*)d_in[10];
  const float* ln1_g  = (const float*)d_in[11];
  const float* ln2_g  = (const float*)d_in[12];
  const float* lnf_g  = (const float*)d_in[13];
  const float* out_w  = (const float*)d_in[14];
  float* logits = (float*)d_out;

  char* w = (char*)d_ws;
  float* x    = (float*)(w);                       // [4096,512]  fp32   8 MB
  short* h    = (short*)(w + (8ll  << 20));        // [4096,512]  bf16   4 MB
  short* qkvb = (short*)(w + (12ll << 20));        // [4096,1536] bf16  12 MB
  short* f1   = (short*)(w + (24ll << 20));        // [4096,2048] bf16  16 MB
  short* wpool= (short*)(w + (40ll << 20));        // bf16 Wt pool    70.6 MB
  short* qkvT = wpool;                             // [6][1536][512]
  short* projT= qkvT + 6ll*1536*512;               // [6][512][512]
  short* fc1T = projT + 6ll*512*512;               // [6][2048][512]
  short* fc2T = fc1T + 6ll*2048*512;               // [6][512][2048]
  short* outT = fc2T + 6ll*512*2048;               // [32000][512]

  // one-time weight convert+transpose (Wt[n][k] = bf16(W[k][n]))
  transpose_k<<<dim3(1536/64, 512/64, L_), 256, 0, stream>>>(qkv_w,  qkvT, 512, 1536);
  transpose_k<<<dim3( 512/64, 512/64, L_), 256, 0, stream>>>(proj_w, projT, 512, 512);
  transpose_k<<<dim3(2048/64, 512/64, L_), 256, 0, stream>>>(fc1_w,  fc1T, 512, 2048);
  transpose_k<<<dim3( 512/64,2048/64, L_), 256, 0, stream>>>(fc2_w,  fc2T, 2048, 512);
  transpose_k<<<dim3(V_/64,   512/64, 1 ), 256, 0, stream>>>(out_w,  outT, 512, V_);

  embed_k<<<M_, 128, 0, stream>>>(ids, tok, pos, x);

  for(int l = 0; l < L_; l++){
    ln_k<<<M_, 128, 0, stream>>>(x, ln1_g + l*E_, h);
    gemm_bf_k<128><<<(M_/128)*(1536/128), 256, 0, stream>>>(
        h, qkvT + (long long)l*1536*512, qkv_b + l*1536, nullptr, qkvb,
        M_, 1536, E_, 0, 1, 0);
    fattn_k<<<(B_*H_) * (S_/64), 256, 0, stream>>>(qkvb, h);
    gemm_bf_k<64><<<(M_/128)*(512/64), 256, 0, stream>>>(
        h, projT + (long long)l*512*512, proj_b + l*E_, x, x,
        M_, E_, E_, 0, 0, 0);
    ln_k<<<M_, 128, 0, stream>>>(x, ln2_g + l*E_, h);
    gemm_bf_k<128><<<(M_/128)*(2048/128), 256, 0, stream>>>(
        h, fc1T + (long long)l*2048*512, fc1_b + l*2048, nullptr, f1,
        M_, 2048, E_, 1, 1, 0);
    gemm_bf_k<64><<<(M_/128)*(512/64), 256, 0, stream>>>(
        f1, fc2T + (long long)l*512*2048, fc2_b + l*E_, x, x,
        M_, E_, 2048, 0, 0, 0);
  }

  ln_k<<<M_, 128, 0, stream>>>(x, lnf_g, h);
  gemm_bf_k<128><<<(M_/128)*(V_/128), 256, 0, stream>>>(
      h, outT, nullptr, nullptr, logits,
      M_, V_, E_, 0, 0, 1);
}